// Round 14
// baseline (794.888 us; speedup 1.0000x reference)
//
#include <hip/hip_runtime.h>

typedef __attribute__((ext_vector_type(8))) short short8;
typedef __attribute__((ext_vector_type(4))) short short4v;
typedef __attribute__((ext_vector_type(4))) float f32x4;

#define TMASK  ((1u << 18) - 1u)
#define PRIME1 2654435761u
#define PRIME2 805459861u

// floor(16*SCALE^k), numpy SCALE = exp(ln(256)/16) rounds one ulp BELOW sqrt(2)
// -> even-k levels are 2^m - 1. Verified: rounds 7-13 PASS.
__constant__ float c_res[16] = {16.f, 22.f, 31.f, 45.f, 63.f, 90.f, 127.f, 181.f,
                                255.f, 362.f, 511.f, 724.f, 1023.f, 1448.f, 2047.f, 2896.f};

__device__ __forceinline__ unsigned short rne_bf16(float v) {
  unsigned u = __builtin_bit_cast(unsigned, v);
  return (unsigned short)((u + 0x7fffu + ((u >> 16) & 1u)) >> 16);
}
__device__ __forceinline__ float b2f(unsigned short h) {
  unsigned u = (unsigned)h << 16;
  return __builtin_bit_cast(float, u);
}

// ============ Kernel E: encode, level-pair -> XCD partitioned (r11, 421us) ============
// blockIdx%8 = g = level pair {2g,2g+1} pinned to one XCD's L2. Even-cx corner
// pairing: 4x16B instead of 8x8B requests (avg 6/level). At the measured
// concurrency ceiling (~225 G lane-req/s) -- needs ~25 waves/CU, hence no LDS.
__global__ __launch_bounds__(256) void encode_lvl(
    const float* __restrict__ X, const float* __restrict__ Tb,
    unsigned short* __restrict__ encF) {
  const int b = blockIdx.x;
  const int g = b & 7;
  const int p = (b >> 3) * 256 + threadIdx.x;

  const float x0 = X[p * 3 + 0];
  const float x1 = X[p * 3 + 1];
  const float x2 = X[p * 3 + 2];

  short4v pk;
#pragma unroll
  for (int li = 0; li < 2; ++li) {
    const int lvl = 2 * g + li;
    const float r = c_res[lvl];
    const float xs0 = x0 * r, xs1 = x1 * r, xs2 = x2 * r;   // plain f32 (jax semantics)
    const float f0 = floorf(xs0), f1 = floorf(xs1), f2 = floorf(xs2);
    const float t0 = xs0 - f0, t1 = xs1 - f1, t2 = xs2 - f2;
    const float w0 = t0 * t0 * (3.f - 2.f * t0);
    const float w1v = t1 * t1 * (3.f - 2.f * t1);
    const float w2v = t2 * t2 * (3.f - 2.f * t2);
    const unsigned cx0 = (unsigned)(int)f0;
    const unsigned hy0 = (unsigned)(int)f1 * PRIME1, hy1 = hy0 + PRIME1;
    const unsigned hz0 = (unsigned)(int)f2 * PRIME2, hz1 = hz0 + PRIME2;
    const float2* tab = reinterpret_cast<const float2*>(Tb) + ((size_t)lvl << 18);
    float a0 = 0.f, a1 = 0.f;
    if (!(cx0 & 1u)) {
      const float4* tab4 = reinterpret_cast<const float4*>(tab);
#pragma unroll
      for (int jk = 0; jk < 4; ++jk) {
        const unsigned hb = (cx0 ^ ((jk & 2) ? hy1 : hy0) ^ ((jk & 1) ? hz1 : hz0)) & TMASK;
        const float4 q = tab4[hb >> 1];
        float e0x, e0y, e1x, e1y;
        if (hb & 1) { e0x = q.z; e0y = q.w; e1x = q.x; e1y = q.y; }
        else        { e0x = q.x; e0y = q.y; e1x = q.z; e1y = q.w; }
        const float wy = (jk & 2) ? w1v : 1.f - w1v;
        const float wz = (jk & 1) ? w2v : 1.f - w2v;
        const float wt0 = ((1.f - w0) * wy) * wz;   // exact ((wx*wy)*wz) order
        const float wt1 = (w0 * wy) * wz;
        a0 = fmaf(e0x, wt0, a0); a1 = fmaf(e0y, wt0, a1);
        a0 = fmaf(e1x, wt1, a0); a1 = fmaf(e1y, wt1, a1);
      }
    } else {
#pragma unroll
      for (int c = 0; c < 8; ++c) {  // OFFS order: c = i*4 + j*2 + k
        const unsigned hx = cx0 + (unsigned)((c >> 2) & 1);
        const unsigned hh = (hx ^ ((c & 2) ? hy1 : hy0) ^ ((c & 1) ? hz1 : hz0)) & TMASK;
        const float2 f = tab[hh];
        const float wt = (((c >> 2) & 1) ? w0 : 1.f - w0) *
                         (((c >> 1) & 1) ? w1v : 1.f - w1v) *
                         (((c & 1)) ? w2v : 1.f - w2v);
        a0 = fmaf(f.x, wt, a0);
        a1 = fmaf(f.y, wt, a1);
      }
    }
    pk[li * 2 + 0] = (short)rne_bf16(a0);
    pk[li * 2 + 1] = (short)rne_bf16(a1);
  }
  const int pl = p & 63, chunk = p >> 6;
  const size_t addr = ((size_t)(chunk * 4 + (pl >> 4)) * 64 +
                       (((g >> 1) << 4) | (pl & 15))) * 8 + (g & 1) * 4;
  *reinterpret_cast<short4v*>(encF + addr) = pk;
}

// ============ Kernel P: W2-hi B-fragments -> ws ============
// blockIdx = c*4+kc (36 blocks); one fragment set = 64 lanes x 16B contiguous.
__global__ __launch_bounds__(64) void prep_w2hi(
    const float* __restrict__ W2, unsigned short* __restrict__ w2hi) {
  const int lane = threadIdx.x;
  const int c = blockIdx.x >> 2, kc = blockIdx.x & 3;
  int bcol = c * 16 + (lane & 15);
  if (bcol > 128) bcol = 128;           // pad cols masked at store
  const int k0 = (kc * 4 + (lane >> 4)) * 8;
  short8 v;
#pragma unroll
  for (int e = 0; e < 8; ++e)
    v[e] = (short)rne_bf16(W2[(size_t)(k0 + e) * 129 + bcol]);
  *reinterpret_cast<short8*>(w2hi + ((size_t)blockIdx.x * 64 + lane) * 8) = v;
}

// ============ Kernel B: MFMA MLP, 42.8KB LDS -> 3 blocks/CU ============
// W2-hi streamed from ws (L1/L2-hot, 36KB); xyz via direct per-thread loads
// (L1 broadcast); output staged in LDS, nontemporal whole-line stores.
__global__ __launch_bounds__(256, 3) void mlp_mfma(
    const float* __restrict__ X, const float* __restrict__ W1,
    const unsigned short* __restrict__ encF, const unsigned short* __restrict__ w2hi,
    float* __restrict__ Out, int nChunks) {
  __shared__ __align__(16) unsigned char lds[42752];
  unsigned short* w1S = (unsigned short*)lds;              // [4 kgrp][128 col][8]  8192 B
  float*          w1x = (float*)(lds + 8192);              // [3][128]              1536 B
  float*          hS  = (float*)(lds + 9728);              // [64][128] fp32       32768 B
  float*          outS = (float*)(lds + 9728);             // [64][129] overlay    33024 B

  const int tid = threadIdx.x;
  const int lane = tid & 63, w = tid >> 6;

  // ---- stage W1 (bf16 fragments + fp32 xyz rows), once per block ----
  for (int idx = tid; idx < 32 * 128; idx += 256) {
    const int k = idx >> 7, col = idx & 127;
    w1S[((k >> 3) * 128 + col) * 8 + (k & 7)] = rne_bf16(W1[(k + 3) * 128 + col]);
  }
  for (int idx = tid; idx < 3 * 128; idx += 256) w1x[idx] = W1[idx];
  __syncthreads();

  const int stride = gridDim.x;
  int chunk = blockIdx.x;

  // ---- prologue: prefetch af + xyz for first chunk ----
  short8 af;
  float xr0[4], xr1[4], xr2[4];
  if (chunk < nChunks) {
    af = *reinterpret_cast<const short8*>(encF + ((size_t)(chunk * 4 + w) * 64 + lane) * 8);
#pragma unroll
    for (int r = 0; r < 4; ++r) {
      const size_t row = (size_t)(chunk << 6) + (w << 4) + (lane >> 4) * 4 + r;
      xr0[r] = X[row * 3 + 0]; xr1[r] = X[row * 3 + 1]; xr2[r] = X[row * 3 + 2];
    }
  }

  for (; chunk < nChunks; chunk += stride) {
    const int row0 = chunk << 6;

    // ---- layer 1: 8 MFMAs (K=32 features) ----
    f32x4 acc1[8];
#pragma unroll
    for (int c = 0; c < 8; ++c) acc1[c] = (f32x4){0.f, 0.f, 0.f, 0.f};
#pragma unroll
    for (int c = 0; c < 8; ++c) {
      const short8 bb = *reinterpret_cast<const short8*>(
          &w1S[((lane >> 4) * 128 + c * 16 + (lane & 15)) * 8]);
      acc1[c] = __builtin_amdgcn_mfma_f32_16x16x32_bf16(af, bb, acc1[c], 0, 0, 0);
    }

    // ---- prefetch next chunk (hides HBM latency behind the whole chunk) ----
    const int nxt = chunk + stride;
    short8 afn;
    float xn0[4], xn1[4], xn2[4];
    if (nxt < nChunks) {
      afn = *reinterpret_cast<const short8*>(encF + ((size_t)(nxt * 4 + w) * 64 + lane) * 8);
#pragma unroll
      for (int r = 0; r < 4; ++r) {
        const size_t row = (size_t)(nxt << 6) + (w << 4) + (lane >> 4) * 4 + r;
        xn0[r] = X[row * 3 + 0]; xn1[r] = X[row * 3 + 1]; xn2[r] = X[row * 3 + 2];
      }
    }

    // ---- exact fp32 xyz rank-3 update ----
#pragma unroll
    for (int r = 0; r < 4; ++r) {
#pragma unroll
      for (int c = 0; c < 8; ++c) {
        const int col = c * 16 + (lane & 15);
        float v = acc1[c][r];
        v = fmaf(xr0[r], w1x[col], v);
        v = fmaf(xr1[r], w1x[128 + col], v);
        v = fmaf(xr2[r], w1x[256 + col], v);
        acc1[c][r] = v;
      }
    }
    // ---- relu -> hS (fp32, 16B-chunk swizzled) ----
#pragma unroll
    for (int c = 0; c < 8; ++c) {
#pragma unroll
      for (int r = 0; r < 4; ++r) {
        const int row = (w << 4) + (lane >> 4) * 4 + r;
        const int col = c * 16 + (lane & 15);
        const int cc = (col >> 2) ^ (row & 7);
        hS[row * 128 + (cc << 2) + (col & 3)] = fmaxf(acc1[c][r], 0.f);
      }
    }
    __syncthreads();   // B2: hS complete

    // ---- layer 2: h hi/lo split (2-term), W2-hi streamed from ws ----
    {
      const int arow = (w << 4) + (lane & 15);
      short8 a2h[4], a2l[4];
#pragma unroll
      for (int kc = 0; kc < 4; ++kc) {
        const int c8 = kc * 4 + (lane >> 4);
        const int base = arow * 128;
        const int cc0 = (2 * c8) ^ (arow & 7);
        const int cc1 = (2 * c8 + 1) ^ (arow & 7);
        const f32x4 q0 = *reinterpret_cast<const f32x4*>(&hS[base + (cc0 << 2)]);
        const f32x4 q1 = *reinterpret_cast<const f32x4*>(&hS[base + (cc1 << 2)]);
#pragma unroll
        for (int e = 0; e < 4; ++e) {
          const unsigned short hi = rne_bf16(q0[e]);
          a2h[kc][e] = (short)hi;
          a2l[kc][e] = (short)rne_bf16(q0[e] - b2f(hi));
        }
#pragma unroll
        for (int e = 0; e < 4; ++e) {
          const unsigned short hi = rne_bf16(q1[e]);
          a2h[kc][4 + e] = (short)hi;
          a2l[kc][4 + e] = (short)rne_bf16(q1[e] - b2f(hi));
        }
      }
      __syncthreads();   // B3: h consumed, outS overlay safe

#pragma unroll
      for (int c = 0; c < 9; ++c) {
        f32x4 acc = (f32x4){0.f, 0.f, 0.f, 0.f};
#pragma unroll
        for (int kc = 0; kc < 4; ++kc) {
          const short8 bh = *reinterpret_cast<const short8*>(
              w2hi + ((size_t)((c * 4 + kc) * 64 + lane)) * 8);
          acc = __builtin_amdgcn_mfma_f32_16x16x32_bf16(a2h[kc], bh, acc, 0, 0, 0);
          acc = __builtin_amdgcn_mfma_f32_16x16x32_bf16(a2l[kc], bh, acc, 0, 0, 0);
        }
        const int col = c * 16 + (lane & 15);
        if (col < 129) {
#pragma unroll
          for (int r = 0; r < 4; ++r) {
            const int lrow = (w << 4) + (lane >> 4) * 4 + r;
            outS[lrow * 129 + col] = acc[r];
          }
        }
      }
    }
    __syncthreads();   // B4: outS complete

    // ---- nontemporal whole-line store (64*129 floats = 516 cache lines) ----
    {
      float* dst = Out + (size_t)row0 * 129;
      const f32x4* src = (const f32x4*)outS;
      for (int i = tid; i < 2064; i += 256)
        __builtin_nontemporal_store(src[i], reinterpret_cast<f32x4*>(dst + 4 * i));
    }
    __syncthreads();   // Bend: copy-out done, hS region reusable
    af = afn;
#pragma unroll
    for (int r = 0; r < 4; ++r) { xr0[r] = xn0[r]; xr1[r] = xn1[r]; xr2[r] = xn2[r]; }
  }
}

// ================= Fallback (round-8 fused kernel, verified) =================
__global__ __launch_bounds__(256) void fused_hashmlp(
    const float* __restrict__ X, const float* __restrict__ Tb,
    const float* __restrict__ W1, const float* __restrict__ W2,
    float* __restrict__ Out, int nChunks) {
  __shared__ __align__(16) unsigned char lds[147968];
  unsigned short* w1hS = (unsigned short*)lds;
  unsigned short* w1lS = w1hS + 128 * 64;
  unsigned short* w2hS = (unsigned short*)(lds + 32768);
  unsigned short* w2lS = w2hS + 129 * 128;
  unsigned short* enchS = (unsigned short*)(lds + 98816);
  unsigned short* enclS = enchS + 64 * 64;
  float*          hS    = (float*)(lds + 115200);
  float*          outS  = (float*)(lds + 98816);

  const int tid = threadIdx.x;
  for (int idx = tid; idx < 128 * 64; idx += 256) {
    int k = idx >> 7, col = idx & 127;
    float v = 0.f;
    if (k < 35) { int r = (k < 32) ? (k + 3) : (k - 32); v = W1[r * 128 + col]; }
    unsigned short hi = rne_bf16(v);
    unsigned short lo = rne_bf16(v - b2f(hi));
    int a = col * 64 + (k ^ ((col & 7) << 3));
    w1hS[a] = hi; w1lS[a] = lo;
  }
  for (int idx = tid; idx < 129 * 128; idx += 256) {
    int k = idx / 129, col = idx - k * 129;
    float v = W2[k * 129 + col];
    unsigned short hi = rne_bf16(v);
    unsigned short lo = rne_bf16(v - b2f(hi));
    int a = col * 128 + (k ^ ((col & 7) << 3));
    w2hS[a] = hi; w2lS[a] = lo;
  }
  __syncthreads();

  const int p = tid >> 2, s = tid & 3, lane = tid & 63, w = tid >> 6;
  for (int chunk = blockIdx.x; chunk < nChunks; chunk += gridDim.x) {
    const int row0 = chunk * 64;
    {
      const int gp = row0 + p;
      const float x0 = X[gp * 3 + 0], x1 = X[gp * 3 + 1], x2 = X[gp * 3 + 2];
      short8 pkh, pkl;
#pragma unroll
      for (int li = 0; li < 4; ++li) {
        const int lvl = (s << 2) + li;
        const float r = c_res[lvl];
        const float xs0 = x0 * r, xs1 = x1 * r, xs2 = x2 * r;
        const float f0 = floorf(xs0), f1 = floorf(xs1), f2 = floorf(xs2);
        const float t0 = xs0 - f0, t1 = xs1 - f1, t2 = xs2 - f2;
        const float w0 = t0 * t0 * (3.f - 2.f * t0);
        const float w1v = t1 * t1 * (3.f - 2.f * t1);
        const float w2v = t2 * t2 * (3.f - 2.f * t2);
        const unsigned cx0 = (unsigned)(int)f0;
        const unsigned hy0 = (unsigned)(int)f1 * PRIME1, hy1 = hy0 + PRIME1;
        const unsigned hz0 = (unsigned)(int)f2 * PRIME2, hz1 = hz0 + PRIME2;
        const float2* tab = reinterpret_cast<const float2*>(Tb) + ((size_t)lvl << 18);
        float a0 = 0.f, a1 = 0.f;
#pragma unroll
        for (int c = 0; c < 8; ++c) {
          const unsigned hx = cx0 + (unsigned)((c >> 2) & 1);
          const unsigned hh = (hx ^ ((c & 2) ? hy1 : hy0) ^ ((c & 1) ? hz1 : hz0)) & TMASK;
          const float2 f = tab[hh];
          const float wt = (((c >> 2) & 1) ? w0 : 1.f - w0) *
                           (((c >> 1) & 1) ? w1v : 1.f - w1v) *
                           (((c & 1)) ? w2v : 1.f - w2v);
          a0 = fmaf(f.x, wt, a0);
          a1 = fmaf(f.y, wt, a1);
        }
        unsigned short h0 = rne_bf16(a0), h1 = rne_bf16(a1);
        pkh[li * 2 + 0] = (short)h0; pkh[li * 2 + 1] = (short)h1;
        pkl[li * 2 + 0] = (short)rne_bf16(a0 - b2f(h0));
        pkl[li * 2 + 1] = (short)rne_bf16(a1 - b2f(h1));
      }
      const int coff = (s ^ (p & 7)) << 3;
      *reinterpret_cast<short8*>(&enchS[p * 64 + coff]) = pkh;
      *reinterpret_cast<short8*>(&enclS[p * 64 + coff]) = pkl;
      short8 zh, zl;
#pragma unroll
      for (int e = 0; e < 8; ++e) { zh[e] = 0; zl[e] = 0; }
      if (s == 0) {
        unsigned short hx0 = rne_bf16(x0), hx1 = rne_bf16(x1), hx2 = rne_bf16(x2);
        zh[0] = (short)hx0; zh[1] = (short)hx1; zh[2] = (short)hx2;
        zl[0] = (short)rne_bf16(x0 - b2f(hx0));
        zl[1] = (short)rne_bf16(x1 - b2f(hx1));
        zl[2] = (short)rne_bf16(x2 - b2f(hx2));
      }
      const int coff2 = ((4 + s) ^ (p & 7)) << 3;
      *reinterpret_cast<short8*>(&enchS[p * 64 + coff2]) = zh;
      *reinterpret_cast<short8*>(&enclS[p * 64 + coff2]) = zl;
    }
    __syncthreads();
    f32x4 acc1[8];
#pragma unroll
    for (int c = 0; c < 8; ++c) acc1[c] = (f32x4){0.f, 0.f, 0.f, 0.f};
    {
      const int arow = (w << 4) + (lane & 15);
#pragma unroll
      for (int kc = 0; kc < 2; ++kc) {
        const int c8 = kc * 4 + (lane >> 4);
        const int aoff = arow * 64 + ((c8 ^ (arow & 7)) << 3);
        const short8 ah = *reinterpret_cast<const short8*>(&enchS[aoff]);
        const short8 al = *reinterpret_cast<const short8*>(&enclS[aoff]);
#pragma unroll
        for (int c = 0; c < 8; ++c) {
          const int bcol = c * 16 + (lane & 15);
          const int boff = bcol * 64 + ((c8 ^ (bcol & 7)) << 3);
          const short8 bh = *reinterpret_cast<const short8*>(&w1hS[boff]);
          const short8 bl = *reinterpret_cast<const short8*>(&w1lS[boff]);
          acc1[c] = __builtin_amdgcn_mfma_f32_16x16x32_bf16(ah, bh, acc1[c], 0, 0, 0);
          acc1[c] = __builtin_amdgcn_mfma_f32_16x16x32_bf16(ah, bl, acc1[c], 0, 0, 0);
          acc1[c] = __builtin_amdgcn_mfma_f32_16x16x32_bf16(al, bh, acc1[c], 0, 0, 0);
        }
      }
    }
#pragma unroll
    for (int c = 0; c < 8; ++c) {
#pragma unroll
      for (int r = 0; r < 4; ++r) {
        const int row = (w << 4) + (lane >> 4) * 4 + r;
        const int col = c * 16 + (lane & 15);
        const int cc = (col >> 2) ^ (row & 7);
        hS[row * 128 + (cc << 2) + (col & 3)] = fmaxf(acc1[c][r], 0.f);
      }
    }
    __syncthreads();
    {
      const int arow = (w << 4) + (lane & 15);
      short8 a2h[4], a2l[4];
#pragma unroll
      for (int kc = 0; kc < 4; ++kc) {
        const int c8 = kc * 4 + (lane >> 4);
        const int base = arow * 128;
        const int cc0 = (2 * c8) ^ (arow & 7);
        const int cc1 = (2 * c8 + 1) ^ (arow & 7);
        const f32x4 q0 = *reinterpret_cast<const f32x4*>(&hS[base + (cc0 << 2)]);
        const f32x4 q1 = *reinterpret_cast<const f32x4*>(&hS[base + (cc1 << 2)]);
#pragma unroll
        for (int e = 0; e < 4; ++e) {
          unsigned short hi = rne_bf16(q0[e]);
          a2h[kc][e] = (short)hi;
          a2l[kc][e] = (short)rne_bf16(q0[e] - b2f(hi));
        }
#pragma unroll
        for (int e = 0; e < 4; ++e) {
          unsigned short hi = rne_bf16(q1[e]);
          a2h[kc][4 + e] = (short)hi;
          a2l[kc][4 + e] = (short)rne_bf16(q1[e] - b2f(hi));
        }
      }
      __syncthreads();
#pragma unroll
      for (int c = 0; c < 9; ++c) {
        f32x4 acc = (f32x4){0.f, 0.f, 0.f, 0.f};
        int bcol = c * 16 + (lane & 15);
        if (bcol > 128) bcol = 128;
#pragma unroll
        for (int kc = 0; kc < 4; ++kc) {
          const int c8 = kc * 4 + (lane >> 4);
          const int boff = bcol * 128 + ((c8 ^ (bcol & 7)) << 3);
          const short8 bh = *reinterpret_cast<const short8*>(&w2hS[boff]);
          const short8 bl = *reinterpret_cast<const short8*>(&w2lS[boff]);
          acc = __builtin_amdgcn_mfma_f32_16x16x32_bf16(a2h[kc], bh, acc, 0, 0, 0);
          acc = __builtin_amdgcn_mfma_f32_16x16x32_bf16(a2h[kc], bl, acc, 0, 0, 0);
          acc = __builtin_amdgcn_mfma_f32_16x16x32_bf16(a2l[kc], bh, acc, 0, 0, 0);
        }
        const int col = c * 16 + (lane & 15);
        if (col < 129) {
#pragma unroll
          for (int r = 0; r < 4; ++r) {
            const int lrow = (w << 4) + (lane >> 4) * 4 + r;
            outS[lrow * 129 + col] = acc[r];
          }
        }
      }
    }
    __syncthreads();
    {
      float* dst = Out + (size_t)row0 * 129;
      const f32x4* src = (const f32x4*)outS;
      for (int i = tid; i < 2064; i += 256)
        *reinterpret_cast<f32x4*>(dst + 4 * i) = src[i];
    }
    __syncthreads();
  }
}

extern "C" void kernel_launch(void* const* d_in, const int* in_sizes, int n_in,
                              void* d_out, int out_size, void* d_ws, size_t ws_size,
                              hipStream_t stream) {
  const float* X  = (const float*)d_in[0];
  const float* Tb = (const float*)d_in[1];
  const float* W1 = (const float*)d_in[2];
  const float* W2 = (const float*)d_in[3];
  float* Out = (float*)d_out;

  const int N = in_sizes[0] / 3;     // 1<<20
  const int nChunks = N / 64;        // 16384

  const size_t encBytes = (size_t)nChunks * 4096;       // 64 MiB bf16 A-fragments
  const size_t w2hiBytes = 36 * 64 * 16;                // 36 KiB
  if (ws_size >= encBytes + w2hiBytes && (N & 255) == 0) {
    unsigned short* encF = (unsigned short*)d_ws;
    unsigned short* w2hi = (unsigned short*)((char*)d_ws + encBytes);
    encode_lvl<<<(N / 256) * 8, 256, 0, stream>>>(X, Tb, encF);
    prep_w2hi<<<36, 64, 0, stream>>>(W2, w2hi);
    mlp_mfma<<<768, 256, 0, stream>>>(X, W1, encF, w2hi, Out, nChunks);
  } else {
    int grid = nChunks < 1024 ? nChunks : 1024;
    fused_hashmlp<<<grid, 256, 0, stream>>>(X, Tb, W1, W2, Out, nChunks);
  }
}

// Round 15
// 558.584 us; speedup vs baseline: 1.4230x; 1.4230x over previous
//
#include <hip/hip_runtime.h>

typedef __attribute__((ext_vector_type(8))) short short8;
typedef __attribute__((ext_vector_type(4))) short short4v;
typedef __attribute__((ext_vector_type(4))) float f32x4;

#define TMASK  ((1u << 18) - 1u)
#define PRIME1 2654435761u
#define PRIME2 805459861u

// floor(16*SCALE^k), numpy SCALE = exp(ln(256)/16) rounds one ulp BELOW sqrt(2)
// -> even-k levels are 2^m - 1. Verified: rounds 7-14 PASS.
__constant__ float c_res[16] = {16.f, 22.f, 31.f, 45.f, 63.f, 90.f, 127.f, 181.f,
                                255.f, 362.f, 511.f, 724.f, 1023.f, 1448.f, 2047.f, 2896.f};

__device__ __forceinline__ unsigned short rne_bf16(float v) {
  unsigned u = __builtin_bit_cast(unsigned, v);
  return (unsigned short)((u + 0x7fffu + ((u >> 16) & 1u)) >> 16);
}
__device__ __forceinline__ float b2f(unsigned short h) {
  unsigned u = (unsigned)h << 16;
  return __builtin_bit_cast(float, u);
}

// ============ Kernel E: encode, level-pair -> XCD partitioned (r11, 421us) ============
// blockIdx%8 = g = level pair {2g,2g+1} pinned to one XCD's L2. Even-cx corner
// pairing: 4x16B instead of 8x8B requests (avg 6/level). Measured at the L2
// random-request concurrency ceiling (~225 G lane-req/s) across r10/r11/r14.
__global__ __launch_bounds__(256) void encode_lvl(
    const float* __restrict__ X, const float* __restrict__ Tb,
    unsigned short* __restrict__ encF) {
  const int b = blockIdx.x;
  const int g = b & 7;
  const int p = (b >> 3) * 256 + threadIdx.x;

  const float x0 = X[p * 3 + 0];
  const float x1 = X[p * 3 + 1];
  const float x2 = X[p * 3 + 2];

  short4v pk;
#pragma unroll
  for (int li = 0; li < 2; ++li) {
    const int lvl = 2 * g + li;
    const float r = c_res[lvl];
    const float xs0 = x0 * r, xs1 = x1 * r, xs2 = x2 * r;   // plain f32 (jax semantics)
    const float f0 = floorf(xs0), f1 = floorf(xs1), f2 = floorf(xs2);
    const float t0 = xs0 - f0, t1 = xs1 - f1, t2 = xs2 - f2;
    const float w0 = t0 * t0 * (3.f - 2.f * t0);
    const float w1v = t1 * t1 * (3.f - 2.f * t1);
    const float w2v = t2 * t2 * (3.f - 2.f * t2);
    const unsigned cx0 = (unsigned)(int)f0;
    const unsigned hy0 = (unsigned)(int)f1 * PRIME1, hy1 = hy0 + PRIME1;
    const unsigned hz0 = (unsigned)(int)f2 * PRIME2, hz1 = hz0 + PRIME2;
    const float2* tab = reinterpret_cast<const float2*>(Tb) + ((size_t)lvl << 18);
    float a0 = 0.f, a1 = 0.f;
    if (!(cx0 & 1u)) {
      const float4* tab4 = reinterpret_cast<const float4*>(tab);
#pragma unroll
      for (int jk = 0; jk < 4; ++jk) {
        const unsigned hb = (cx0 ^ ((jk & 2) ? hy1 : hy0) ^ ((jk & 1) ? hz1 : hz0)) & TMASK;
        const float4 q = tab4[hb >> 1];
        float e0x, e0y, e1x, e1y;
        if (hb & 1) { e0x = q.z; e0y = q.w; e1x = q.x; e1y = q.y; }
        else        { e0x = q.x; e0y = q.y; e1x = q.z; e1y = q.w; }
        const float wy = (jk & 2) ? w1v : 1.f - w1v;
        const float wz = (jk & 1) ? w2v : 1.f - w2v;
        const float wt0 = ((1.f - w0) * wy) * wz;   // exact ((wx*wy)*wz) order
        const float wt1 = (w0 * wy) * wz;
        a0 = fmaf(e0x, wt0, a0); a1 = fmaf(e0y, wt0, a1);
        a0 = fmaf(e1x, wt1, a0); a1 = fmaf(e1y, wt1, a1);
      }
    } else {
#pragma unroll
      for (int c = 0; c < 8; ++c) {  // OFFS order: c = i*4 + j*2 + k
        const unsigned hx = cx0 + (unsigned)((c >> 2) & 1);
        const unsigned hh = (hx ^ ((c & 2) ? hy1 : hy0) ^ ((c & 1) ? hz1 : hz0)) & TMASK;
        const float2 f = tab[hh];
        const float wt = (((c >> 2) & 1) ? w0 : 1.f - w0) *
                         (((c >> 1) & 1) ? w1v : 1.f - w1v) *
                         (((c & 1)) ? w2v : 1.f - w2v);
        a0 = fmaf(f.x, wt, a0);
        a1 = fmaf(f.y, wt, a1);
      }
    }
    pk[li * 2 + 0] = (short)rne_bf16(a0);
    pk[li * 2 + 1] = (short)rne_bf16(a1);
  }
  const int pl = p & 63, chunk = p >> 6;
  const size_t addr = ((size_t)(chunk * 4 + (pl >> 4)) * 64 +
                       (((g >> 1) << 4) | (pl & 15))) * 8 + (g & 1) * 4;
  *reinterpret_cast<short4v*>(encF + addr) = pk;
}

// ============ Kernel B: MFMA MLP (exact r11 structure, 578us total) ============
// W2 single-bf16 in LDS; h hi/lo split (2-term MFMA); af+xyz prefetched one
// chunk ahead. ONLY change vs r11: nontemporal output stores (528MB stream
// bypasses L2 -> no write-allocate pollution of the hot caches).
__global__ __launch_bounds__(256, 2) void mlp_mfma(
    const float* __restrict__ X, const float* __restrict__ W1,
    const float* __restrict__ W2, const unsigned short* __restrict__ encF,
    float* __restrict__ Out, int nChunks) {
  __shared__ __align__(16) unsigned char lds[76800];
  unsigned short* w1S  = (unsigned short*)lds;             // [4 c8][128 col][8]  8192 B
  float*          w1x  = (float*)(lds + 8192);             // [3][128]            1536 B
  float*          xyzS = (float*)(lds + 9728);             // [64][4]             1024 B
  unsigned short* w2hS = (unsigned short*)(lds + 10752);   // [16 c8][129][8]    33024 B
  float*          hS   = (float*)(lds + 43776);            // [64][128] fp32
  float*          outS = (float*)(lds + 43776);            // [64][129] overlay  33024 B

  const int tid = threadIdx.x;
  const int lane = tid & 63, w = tid >> 6;

  // ---- stage weights (once per block) ----
  for (int idx = tid; idx < 32 * 128; idx += 256) {
    const int k = idx >> 7, col = idx & 127;
    w1S[((k >> 3) * 128 + col) * 8 + (k & 7)] = rne_bf16(W1[(k + 3) * 128 + col]);
  }
  for (int idx = tid; idx < 3 * 128; idx += 256) w1x[idx] = W1[idx];
  for (int idx = tid; idx < 128 * 129; idx += 256) {
    const int k = idx / 129, col = idx - k * 129;
    w2hS[((k >> 3) * 129 + col) * 8 + (k & 7)] = rne_bf16(W2[idx]);
  }
  __syncthreads();

  const int stride = gridDim.x;
  int chunk = blockIdx.x;

  short8 af;
  float xv = 0.f;
  if (chunk < nChunks) {
    af = *reinterpret_cast<const short8*>(encF + ((size_t)(chunk * 4 + w) * 64 + lane) * 8);
    if (tid < 192) xv = X[(size_t)(chunk << 6) * 3 + tid];
  }

  for (; chunk < nChunks; chunk += stride) {
    const int row0 = chunk << 6;
    if (tid < 192) xyzS[(tid / 3) * 4 + (tid % 3)] = xv;
    __syncthreads();   // B1

    // ---- layer 1: 8 MFMAs (K=32 features, single bf16) ----
    f32x4 acc1[8];
#pragma unroll
    for (int c = 0; c < 8; ++c) acc1[c] = (f32x4){0.f, 0.f, 0.f, 0.f};
#pragma unroll
    for (int c = 0; c < 8; ++c) {
      const short8 b = *reinterpret_cast<const short8*>(
          &w1S[((lane >> 4) * 128 + c * 16 + (lane & 15)) * 8]);
      acc1[c] = __builtin_amdgcn_mfma_f32_16x16x32_bf16(af, b, acc1[c], 0, 0, 0);
    }

    // ---- prefetch next chunk ----
    const int nxt = chunk + stride;
    short8 afn;
    if (nxt < nChunks) {
      afn = *reinterpret_cast<const short8*>(encF + ((size_t)(nxt * 4 + w) * 64 + lane) * 8);
      if (tid < 192) xv = X[(size_t)(nxt << 6) * 3 + tid];
    }

    // ---- exact fp32 xyz rank-3 update ----
#pragma unroll
    for (int r = 0; r < 4; ++r) {
      const int grow = (w << 4) + (lane >> 4) * 4 + r;
      const float xs0 = xyzS[grow * 4 + 0];
      const float xs1 = xyzS[grow * 4 + 1];
      const float xs2 = xyzS[grow * 4 + 2];
#pragma unroll
      for (int c = 0; c < 8; ++c) {
        const int col = c * 16 + (lane & 15);
        float v = acc1[c][r];
        v = fmaf(xs0, w1x[col], v);
        v = fmaf(xs1, w1x[128 + col], v);
        v = fmaf(xs2, w1x[256 + col], v);
        acc1[c][r] = v;
      }
    }
    // ---- relu -> hS (fp32, 16B-chunk swizzled) ----
#pragma unroll
    for (int c = 0; c < 8; ++c) {
#pragma unroll
      for (int r = 0; r < 4; ++r) {
        const int row = (w << 4) + (lane >> 4) * 4 + r;
        const int col = c * 16 + (lane & 15);
        const int cc = (col >> 2) ^ (row & 7);
        hS[row * 128 + (cc << 2) + (col & 3)] = fmaxf(acc1[c][r], 0.f);
      }
    }
    __syncthreads();   // B2

    // ---- layer 2: h hi/lo split (2-term), W2 single-bf16 from LDS ----
    {
      const int arow = (w << 4) + (lane & 15);
      short8 a2h[4], a2l[4];
#pragma unroll
      for (int kc = 0; kc < 4; ++kc) {
        const int c8 = kc * 4 + (lane >> 4);
        const int base = arow * 128;
        const int cc0 = (2 * c8) ^ (arow & 7);
        const int cc1 = (2 * c8 + 1) ^ (arow & 7);
        const f32x4 q0 = *reinterpret_cast<const f32x4*>(&hS[base + (cc0 << 2)]);
        const f32x4 q1 = *reinterpret_cast<const f32x4*>(&hS[base + (cc1 << 2)]);
#pragma unroll
        for (int e = 0; e < 4; ++e) {
          const unsigned short hi = rne_bf16(q0[e]);
          a2h[kc][e] = (short)hi;
          a2l[kc][e] = (short)rne_bf16(q0[e] - b2f(hi));
        }
#pragma unroll
        for (int e = 0; e < 4; ++e) {
          const unsigned short hi = rne_bf16(q1[e]);
          a2h[kc][4 + e] = (short)hi;
          a2l[kc][4 + e] = (short)rne_bf16(q1[e] - b2f(hi));
        }
      }
      __syncthreads();   // B3: h consumed, outS overlay safe

#pragma unroll
      for (int c = 0; c < 9; ++c) {
        f32x4 acc = (f32x4){0.f, 0.f, 0.f, 0.f};
        int bcol = c * 16 + (lane & 15);
        if (bcol > 128) bcol = 128;
#pragma unroll
        for (int kc = 0; kc < 4; ++kc) {
          const int c8 = kc * 4 + (lane >> 4);
          const short8 bh = *reinterpret_cast<const short8*>(&w2hS[(c8 * 129 + bcol) * 8]);
          acc = __builtin_amdgcn_mfma_f32_16x16x32_bf16(a2h[kc], bh, acc, 0, 0, 0);
          acc = __builtin_amdgcn_mfma_f32_16x16x32_bf16(a2l[kc], bh, acc, 0, 0, 0);
        }
        const int col = c * 16 + (lane & 15);
        if (col < 129) {
#pragma unroll
          for (int r = 0; r < 4; ++r) {
            const int lrow = (w << 4) + (lane >> 4) * 4 + r;
            outS[lrow * 129 + col] = acc[r];
          }
        }
      }
    }
    __syncthreads();   // B4

    // ---- whole-line store, nontemporal (the single change vs r11) ----
    {
      float* dst = Out + (size_t)row0 * 129;
      const f32x4* src = (const f32x4*)outS;
      for (int i = tid; i < 2064; i += 256)
        __builtin_nontemporal_store(src[i], reinterpret_cast<f32x4*>(dst + 4 * i));
    }
    af = afn;
  }
}

// ================= Fallback (round-8 fused kernel, verified) =================
__global__ __launch_bounds__(256) void fused_hashmlp(
    const float* __restrict__ X, const float* __restrict__ Tb,
    const float* __restrict__ W1, const float* __restrict__ W2,
    float* __restrict__ Out, int nChunks) {
  __shared__ __align__(16) unsigned char lds[147968];
  unsigned short* w1hS = (unsigned short*)lds;
  unsigned short* w1lS = w1hS + 128 * 64;
  unsigned short* w2hS = (unsigned short*)(lds + 32768);
  unsigned short* w2lS = w2hS + 129 * 128;
  unsigned short* enchS = (unsigned short*)(lds + 98816);
  unsigned short* enclS = enchS + 64 * 64;
  float*          hS    = (float*)(lds + 115200);
  float*          outS  = (float*)(lds + 98816);

  const int tid = threadIdx.x;
  for (int idx = tid; idx < 128 * 64; idx += 256) {
    int k = idx >> 7, col = idx & 127;
    float v = 0.f;
    if (k < 35) { int r = (k < 32) ? (k + 3) : (k - 32); v = W1[r * 128 + col]; }
    unsigned short hi = rne_bf16(v);
    unsigned short lo = rne_bf16(v - b2f(hi));
    int a = col * 64 + (k ^ ((col & 7) << 3));
    w1hS[a] = hi; w1lS[a] = lo;
  }
  for (int idx = tid; idx < 129 * 128; idx += 256) {
    int k = idx / 129, col = idx - k * 129;
    float v = W2[k * 129 + col];
    unsigned short hi = rne_bf16(v);
    unsigned short lo = rne_bf16(v - b2f(hi));
    int a = col * 128 + (k ^ ((col & 7) << 3));
    w2hS[a] = hi; w2lS[a] = lo;
  }
  __syncthreads();

  const int p = tid >> 2, s = tid & 3, lane = tid & 63, w = tid >> 6;
  for (int chunk = blockIdx.x; chunk < nChunks; chunk += gridDim.x) {
    const int row0 = chunk * 64;
    {
      const int gp = row0 + p;
      const float x0 = X[gp * 3 + 0], x1 = X[gp * 3 + 1], x2 = X[gp * 3 + 2];
      short8 pkh, pkl;
#pragma unroll
      for (int li = 0; li < 4; ++li) {
        const int lvl = (s << 2) + li;
        const float r = c_res[lvl];
        const float xs0 = x0 * r, xs1 = x1 * r, xs2 = x2 * r;
        const float f0 = floorf(xs0), f1 = floorf(xs1), f2 = floorf(xs2);
        const float t0 = xs0 - f0, t1 = xs1 - f1, t2 = xs2 - f2;
        const float w0 = t0 * t0 * (3.f - 2.f * t0);
        const float w1v = t1 * t1 * (3.f - 2.f * t1);
        const float w2v = t2 * t2 * (3.f - 2.f * t2);
        const unsigned cx0 = (unsigned)(int)f0;
        const unsigned hy0 = (unsigned)(int)f1 * PRIME1, hy1 = hy0 + PRIME1;
        const unsigned hz0 = (unsigned)(int)f2 * PRIME2, hz1 = hz0 + PRIME2;
        const float2* tab = reinterpret_cast<const float2*>(Tb) + ((size_t)lvl << 18);
        float a0 = 0.f, a1 = 0.f;
#pragma unroll
        for (int c = 0; c < 8; ++c) {
          const unsigned hx = cx0 + (unsigned)((c >> 2) & 1);
          const unsigned hh = (hx ^ ((c & 2) ? hy1 : hy0) ^ ((c & 1) ? hz1 : hz0)) & TMASK;
          const float2 f = tab[hh];
          const float wt = (((c >> 2) & 1) ? w0 : 1.f - w0) *
                           (((c >> 1) & 1) ? w1v : 1.f - w1v) *
                           (((c & 1)) ? w2v : 1.f - w2v);
          a0 = fmaf(f.x, wt, a0);
          a1 = fmaf(f.y, wt, a1);
        }
        unsigned short h0 = rne_bf16(a0), h1 = rne_bf16(a1);
        pkh[li * 2 + 0] = (short)h0; pkh[li * 2 + 1] = (short)h1;
        pkl[li * 2 + 0] = (short)rne_bf16(a0 - b2f(h0));
        pkl[li * 2 + 1] = (short)rne_bf16(a1 - b2f(h1));
      }
      const int coff = (s ^ (p & 7)) << 3;
      *reinterpret_cast<short8*>(&enchS[p * 64 + coff]) = pkh;
      *reinterpret_cast<short8*>(&enclS[p * 64 + coff]) = pkl;
      short8 zh, zl;
#pragma unroll
      for (int e = 0; e < 8; ++e) { zh[e] = 0; zl[e] = 0; }
      if (s == 0) {
        unsigned short hx0 = rne_bf16(x0), hx1 = rne_bf16(x1), hx2 = rne_bf16(x2);
        zh[0] = (short)hx0; zh[1] = (short)hx1; zh[2] = (short)hx2;
        zl[0] = (short)rne_bf16(x0 - b2f(hx0));
        zl[1] = (short)rne_bf16(x1 - b2f(hx1));
        zl[2] = (short)rne_bf16(x2 - b2f(hx2));
      }
      const int coff2 = ((4 + s) ^ (p & 7)) << 3;
      *reinterpret_cast<short8*>(&enchS[p * 64 + coff2]) = zh;
      *reinterpret_cast<short8*>(&enclS[p * 64 + coff2]) = zl;
    }
    __syncthreads();
    f32x4 acc1[8];
#pragma unroll
    for (int c = 0; c < 8; ++c) acc1[c] = (f32x4){0.f, 0.f, 0.f, 0.f};
    {
      const int arow = (w << 4) + (lane & 15);
#pragma unroll
      for (int kc = 0; kc < 2; ++kc) {
        const int c8 = kc * 4 + (lane >> 4);
        const int aoff = arow * 64 + ((c8 ^ (arow & 7)) << 3);
        const short8 ah = *reinterpret_cast<const short8*>(&enchS[aoff]);
        const short8 al = *reinterpret_cast<const short8*>(&enclS[aoff]);
#pragma unroll
        for (int c = 0; c < 8; ++c) {
          const int bcol = c * 16 + (lane & 15);
          const int boff = bcol * 64 + ((c8 ^ (bcol & 7)) << 3);
          const short8 bh = *reinterpret_cast<const short8*>(&w1hS[boff]);
          const short8 bl = *reinterpret_cast<const short8*>(&w1lS[boff]);
          acc1[c] = __builtin_amdgcn_mfma_f32_16x16x32_bf16(ah, bh, acc1[c], 0, 0, 0);
          acc1[c] = __builtin_amdgcn_mfma_f32_16x16x32_bf16(ah, bl, acc1[c], 0, 0, 0);
          acc1[c] = __builtin_amdgcn_mfma_f32_16x16x32_bf16(al, bh, acc1[c], 0, 0, 0);
        }
      }
    }
#pragma unroll
    for (int c = 0; c < 8; ++c) {
#pragma unroll
      for (int r = 0; r < 4; ++r) {
        const int row = (w << 4) + (lane >> 4) * 4 + r;
        const int col = c * 16 + (lane & 15);
        const int cc = (col >> 2) ^ (row & 7);
        hS[row * 128 + (cc << 2) + (col & 3)] = fmaxf(acc1[c][r], 0.f);
      }
    }
    __syncthreads();
    {
      const int arow = (w << 4) + (lane & 15);
      short8 a2h[4], a2l[4];
#pragma unroll
      for (int kc = 0; kc < 4; ++kc) {
        const int c8 = kc * 4 + (lane >> 4);
        const int base = arow * 128;
        const int cc0 = (2 * c8) ^ (arow & 7);
        const int cc1 = (2 * c8 + 1) ^ (arow & 7);
        const f32x4 q0 = *reinterpret_cast<const f32x4*>(&hS[base + (cc0 << 2)]);
        const f32x4 q1 = *reinterpret_cast<const f32x4*>(&hS[base + (cc1 << 2)]);
#pragma unroll
        for (int e = 0; e < 4; ++e) {
          unsigned short hi = rne_bf16(q0[e]);
          a2h[kc][e] = (short)hi;
          a2l[kc][e] = (short)rne_bf16(q0[e] - b2f(hi));
        }
#pragma unroll
        for (int e = 0; e < 4; ++e) {
          unsigned short hi = rne_bf16(q1[e]);
          a2h[kc][4 + e] = (short)hi;
          a2l[kc][4 + e] = (short)rne_bf16(q1[e] - b2f(hi));
        }
      }
      __syncthreads();
#pragma unroll
      for (int c = 0; c < 9; ++c) {
        f32x4 acc = (f32x4){0.f, 0.f, 0.f, 0.f};
        int bcol = c * 16 + (lane & 15);
        if (bcol > 128) bcol = 128;
#pragma unroll
        for (int kc = 0; kc < 4; ++kc) {
          const int c8 = kc * 4 + (lane >> 4);
          const int boff = bcol * 128 + ((c8 ^ (bcol & 7)) << 3);
          const short8 bh = *reinterpret_cast<const short8*>(&w2hS[boff]);
          const short8 bl = *reinterpret_cast<const short8*>(&w2lS[boff]);
          acc = __builtin_amdgcn_mfma_f32_16x16x32_bf16(a2h[kc], bh, acc, 0, 0, 0);
          acc = __builtin_amdgcn_mfma_f32_16x16x32_bf16(a2h[kc], bl, acc, 0, 0, 0);
          acc = __builtin_amdgcn_mfma_f32_16x16x32_bf16(a2l[kc], bh, acc, 0, 0, 0);
        }
        const int col = c * 16 + (lane & 15);
        if (col < 129) {
#pragma unroll
          for (int r = 0; r < 4; ++r) {
            const int lrow = (w << 4) + (lane >> 4) * 4 + r;
            outS[lrow * 129 + col] = acc[r];
          }
        }
      }
    }
    __syncthreads();
    {
      float* dst = Out + (size_t)row0 * 129;
      const f32x4* src = (const f32x4*)outS;
      for (int i = tid; i < 2064; i += 256)
        *reinterpret_cast<f32x4*>(dst + 4 * i) = src[i];
    }
    __syncthreads();
  }
}

extern "C" void kernel_launch(void* const* d_in, const int* in_sizes, int n_in,
                              void* d_out, int out_size, void* d_ws, size_t ws_size,
                              hipStream_t stream) {
  const float* X  = (const float*)d_in[0];
  const float* Tb = (const float*)d_in[1];
  const float* W1 = (const float*)d_in[2];
  const float* W2 = (const float*)d_in[3];
  float* Out = (float*)d_out;

  const int N = in_sizes[0] / 3;     // 1<<20
  const int nChunks = N / 64;        // 16384

  const size_t encBytes = (size_t)nChunks * 4096;       // 64 MiB bf16 A-fragments
  if (ws_size >= encBytes && (N & 255) == 0) {
    unsigned short* encF = (unsigned short*)d_ws;
    encode_lvl<<<(N / 256) * 8, 256, 0, stream>>>(X, Tb, encF);
    mlp_mfma<<<2048, 256, 0, stream>>>(X, W1, W2, encF, Out, nChunks);
  } else {
    int grid = nChunks < 1024 ? nChunks : 1024;
    fused_hashmlp<<<grid, 256, 0, stream>>>(X, Tb, W1, W2, Out, nChunks);
  }
}